// Round 1
// baseline (108.601 us; speedup 1.0000x reference)
//
#include <hip/hip_runtime.h>

// MaskCostVolumeLoss: scalar = sum(w * min_shift(mean_c |pred - target_shift|)) / sum(w)
// over interior pixels only (2-px border masked out). N=4, C=3, H=W=512, K=5, P=2.

#define KK 5
#define PP 2
#define NN 4
#define CC 3
#define HH 512
#define WW 512
#define HI 508           // interior rows (y = 2..509)
#define WI4 127          // interior cols / 4 (x0 = 2 + 4*tx, tx in [0,127))

__global__ __launch_bounds__(256) void cvloss_main(
    const float* __restrict__ pred,
    const float* __restrict__ target,
    const float* __restrict__ weight,
    float* __restrict__ acc)   // acc[0]=numerator, acc[1]=denominator
{
    const int tid = blockIdx.x * blockDim.x + threadIdx.x;
    const int total = NN * HI * WI4;

    float num = 0.f, den = 0.f;

    if (tid < total) {
        const int tx   = tid % WI4;
        const int rest = tid / WI4;
        const int y    = rest % HI + PP;
        const int n    = rest / HI;
        const int x0   = 4 * tx + PP;          // x0 - PP = 4*tx -> 16B aligned

        const size_t plane = (size_t)HH * WW;
        const float* pn = pred   + (size_t)n * CC * plane;
        const float* tn = target + (size_t)n * CC * plane;

        // pred: 3 channels x 4 pixels (8B-aligned float2 pairs)
        float p[3][4];
        #pragma unroll
        for (int c = 0; c < 3; ++c) {
            const float2* row = (const float2*)(pn + c * plane + (size_t)y * WW + x0);
            float2 a = row[0], b = row[1];
            p[c][0] = a.x; p[c][1] = a.y; p[c][2] = b.x; p[c][3] = b.y;
        }

        float mn[4] = {1e30f, 1e30f, 1e30f, 1e30f};

        #pragma unroll
        for (int dy = 0; dy < KK; ++dy) {
            // target rows: 3 channels x 8 floats covering x0-2 .. x0+5 (16B aligned)
            float t[3][8];
            #pragma unroll
            for (int c = 0; c < 3; ++c) {
                const float4* r = (const float4*)(tn + c * plane
                                   + (size_t)(y + dy - PP) * WW + (x0 - PP));
                float4 a = r[0], b = r[1];
                t[c][0]=a.x; t[c][1]=a.y; t[c][2]=a.z; t[c][3]=a.w;
                t[c][4]=b.x; t[c][5]=b.y; t[c][6]=b.z; t[c][7]=b.w;
            }
            #pragma unroll
            for (int dx = 0; dx < KK; ++dx) {
                #pragma unroll
                for (int j = 0; j < 4; ++j) {
                    float s = fabsf(p[0][j] - t[0][dx + j])
                            + fabsf(p[1][j] - t[1][dx + j])
                            + fabsf(p[2][j] - t[2][dx + j]);
                    mn[j] = fminf(mn[j], s);
                }
            }
        }

        const float2* wrow = (const float2*)(weight + (size_t)n * CC * plane
                                             + (size_t)y * WW + x0);
        float2 wa = wrow[0], wb = wrow[1];
        float w4[4] = {wa.x, wa.y, wb.x, wb.y};
        #pragma unroll
        for (int j = 0; j < 4; ++j) {
            num += w4[j] * mn[j];
            den += w4[j];
        }
        num *= (1.f / 3.f);   // mean over channels
    }

    // wave (64-lane) shuffle reduction
    #pragma unroll
    for (int o = 32; o > 0; o >>= 1) {
        num += __shfl_down(num, o);
        den += __shfl_down(den, o);
    }

    __shared__ float snum[4], sden[4];
    const int lane = threadIdx.x & 63;
    const int wv   = threadIdx.x >> 6;
    if (lane == 0) { snum[wv] = num; sden[wv] = den; }
    __syncthreads();
    if (threadIdx.x == 0) {
        float bn = snum[0] + snum[1] + snum[2] + snum[3];
        float bd = sden[0] + sden[1] + sden[2] + sden[3];
        atomicAdd(&acc[0], bn);
        atomicAdd(&acc[1], bd);
    }
}

__global__ void cvloss_finalize(const float* __restrict__ acc, float* __restrict__ out)
{
    out[0] = acc[0] / acc[1];
}

extern "C" void kernel_launch(void* const* d_in, const int* in_sizes, int n_in,
                              void* d_out, int out_size, void* d_ws, size_t ws_size,
                              hipStream_t stream) {
    const float* pred   = (const float*)d_in[0];
    const float* target = (const float*)d_in[1];
    const float* weight = (const float*)d_in[2];
    float* out = (float*)d_out;
    float* acc = (float*)d_ws;

    // d_ws is poisoned to 0xAA before every call — zero the accumulators.
    hipMemsetAsync(acc, 0, 2 * sizeof(float), stream);

    const int total  = NN * HI * WI4;        // 258,064 threads
    const int blocks = (total + 255) / 256;  // 1009 blocks
    cvloss_main<<<blocks, 256, 0, stream>>>(pred, target, weight, acc);
    cvloss_finalize<<<1, 1, 0, stream>>>(acc, out);
}

// Round 2
// 84.754 us; speedup vs baseline: 1.2814x; 1.2814x over previous
//
#include <hip/hip_runtime.h>

// MaskCostVolumeLoss: scalar = sum(w * min_shift(mean_c |pred - target_shift|)) / sum(w)
// over interior pixels only (2-px border masked). N=4, C=3, H=W=512, K=5, P=2.
// Two-kernel plan: (1) grid-stride main -> per-block partial sums written (not
// accumulated) to d_ws; (2) single-block reduce + divide. No memset, no atomics.

#define KK 5
#define PP 2
#define NN 4
#define CC 3
#define HH 512
#define WW 512
#define HI 508           // interior rows (y = 2..509)
#define WI4 127          // interior cols / 4 (x0 = 2 + 4*tx, tx in [0,127))
#define NBLK 512         // main-kernel blocks; d_ws holds NBLK float2 partials

__global__ __launch_bounds__(256) void cvloss_main(
    const float* __restrict__ pred,
    const float* __restrict__ target,
    const float* __restrict__ weight,
    float2* __restrict__ partials)   // partials[b] = {num, den}
{
    const int total = NN * HI * WI4;                 // 258,064 pixel-quads
    const int stride = NBLK * 256;

    float num = 0.f, den = 0.f;

    for (int tid = blockIdx.x * 256 + threadIdx.x; tid < total; tid += stride) {
        const int tx   = tid % WI4;
        const int rest = tid / WI4;
        const int y    = rest % HI + PP;
        const int n    = rest / HI;
        const int x0   = 4 * tx + PP;                // x0 - PP = 4*tx -> 16B aligned

        const size_t plane = (size_t)HH * WW;
        const float* pn = pred   + (size_t)n * CC * plane;
        const float* tn = target + (size_t)n * CC * plane;

        // pred: 3 channels x 4 pixels (8B-aligned float2 pairs)
        float p[3][4];
        #pragma unroll
        for (int c = 0; c < 3; ++c) {
            const float2* row = (const float2*)(pn + c * plane + (size_t)y * WW + x0);
            float2 a = row[0], b = row[1];
            p[c][0] = a.x; p[c][1] = a.y; p[c][2] = b.x; p[c][3] = b.y;
        }

        float mn[4] = {1e30f, 1e30f, 1e30f, 1e30f};

        #pragma unroll
        for (int dy = 0; dy < KK; ++dy) {
            float t[3][8];
            #pragma unroll
            for (int c = 0; c < 3; ++c) {
                const float4* r = (const float4*)(tn + c * plane
                                   + (size_t)(y + dy - PP) * WW + (x0 - PP));
                float4 a = r[0], b = r[1];
                t[c][0]=a.x; t[c][1]=a.y; t[c][2]=a.z; t[c][3]=a.w;
                t[c][4]=b.x; t[c][5]=b.y; t[c][6]=b.z; t[c][7]=b.w;
            }
            #pragma unroll
            for (int dx = 0; dx < KK; ++dx) {
                #pragma unroll
                for (int j = 0; j < 4; ++j) {
                    float s = fabsf(p[0][j] - t[0][dx + j])
                            + fabsf(p[1][j] - t[1][dx + j])
                            + fabsf(p[2][j] - t[2][dx + j]);
                    mn[j] = fminf(mn[j], s);
                }
            }
        }

        const float2* wrow = (const float2*)(weight + (size_t)n * CC * plane
                                             + (size_t)y * WW + x0);
        float2 wa = wrow[0], wb = wrow[1];
        num += wa.x * mn[0] + wa.y * mn[1] + wb.x * mn[2] + wb.y * mn[3];
        den += wa.x + wa.y + wb.x + wb.y;
    }

    num *= (1.f / 3.f);   // mean over channels

    // wave (64-lane) shuffle reduction
    #pragma unroll
    for (int o = 32; o > 0; o >>= 1) {
        num += __shfl_down(num, o);
        den += __shfl_down(den, o);
    }

    __shared__ float snum[4], sden[4];
    const int lane = threadIdx.x & 63;
    const int wv   = threadIdx.x >> 6;
    if (lane == 0) { snum[wv] = num; sden[wv] = den; }
    __syncthreads();
    if (threadIdx.x == 0) {
        float2 out;
        out.x = snum[0] + snum[1] + snum[2] + snum[3];
        out.y = sden[0] + sden[1] + sden[2] + sden[3];
        partials[blockIdx.x] = out;   // plain write: no zero-init needed
    }
}

__global__ __launch_bounds__(256) void cvloss_reduce(
    const float2* __restrict__ partials, float* __restrict__ out)
{
    const int t = threadIdx.x;
    float2 a = partials[t];
    float2 b = partials[t + 256];
    float num = a.x + b.x;
    float den = a.y + b.y;

    #pragma unroll
    for (int o = 32; o > 0; o >>= 1) {
        num += __shfl_down(num, o);
        den += __shfl_down(den, o);
    }

    __shared__ float snum[4], sden[4];
    const int lane = t & 63;
    const int wv   = t >> 6;
    if (lane == 0) { snum[wv] = num; sden[wv] = den; }
    __syncthreads();
    if (t == 0) {
        float bn = snum[0] + snum[1] + snum[2] + snum[3];
        float bd = sden[0] + sden[1] + sden[2] + sden[3];
        out[0] = bn / bd;
    }
}

extern "C" void kernel_launch(void* const* d_in, const int* in_sizes, int n_in,
                              void* d_out, int out_size, void* d_ws, size_t ws_size,
                              hipStream_t stream) {
    const float* pred   = (const float*)d_in[0];
    const float* target = (const float*)d_in[1];
    const float* weight = (const float*)d_in[2];
    float* out = (float*)d_out;
    float2* partials = (float2*)d_ws;

    cvloss_main<<<NBLK, 256, 0, stream>>>(pred, target, weight, partials);
    cvloss_reduce<<<1, 256, 0, stream>>>(partials, out);
}